// Round 7
// baseline (319.072 us; speedup 1.0000x reference)
//
#include <hip/hip_runtime.h>

#define BATCH 16
#define TXT   320
#define NMELC 80
#define MELT  2000
#define DIAG  2368   // >= MELT + TXT - 1 + slack, multiple of 8
#define PADM  1.0e12f
#define EPSC  1e-7f
#define L2E   1.4426950408889634f
#define LN2   0.6931471805599453f
#define EPSL2 1.4426950e-7f
#define KZERO (-1073741824)

// ---------------------------------------------------------------------------
// Kernel A: log_prob[b,j,t] = s*(xx - 2xm + mm),  s = -0.5/80
// tile 64j x 256t, 256 threads, 8j x 8t per thread (r5 structure, 21KB LDS).
// lpS[b][t+j][j] = exp2(lp*L2E + EPS*L2E)  — LINEAR-domain p for the DP.
// ---------------------------------------------------------------------------
__global__ __launch_bounds__(256) void lp_kernel(
    const float* __restrict__ mlv,   // (B,320,160)
    const float* __restrict__ ms,    // (B,80,2000)
    float* __restrict__ out_lp,      // (B,320,2000)  (d_out+1)
    float* __restrict__ lpS,         // (B,DIAG,320) skewed scratch or null
    int has_S)
{
    __shared__ float Gt[16][64];
    __shared__ float Ft[16][256];
    __shared__ float bias_s[64];
    __shared__ float bias_p[256];

    const int b   = blockIdx.z;
    const int j0  = blockIdx.y * 64;
    const int t0  = blockIdx.x * 256;
    const int tid = threadIdx.x;
    const float s = -0.00625f;  // -0.5/80

    const float* mlv_b = mlv + (size_t)b * TXT * 160;
    const float* ms_b  = ms  + (size_t)b * NMELC * MELT;

    {
        const int jj = tid >> 2;
        const int q  = tid & 3;
        const float* p = mlv_b + (size_t)(j0 + jj) * 160 + q * 20;
        float part = 0.f;
        #pragma unroll
        for (int c = 0; c < 20; ++c) {
            float mu = p[c];
            float lv = p[c + 80];
            float iv = __expf(-lv);
            part += mu * mu * iv + lv;
        }
        bias_p[tid] = part;
    }
    __syncthreads();
    if (tid < 64) {
        float v = bias_p[tid * 4] + bias_p[tid * 4 + 1] +
                  bias_p[tid * 4 + 2] + bias_p[tid * 4 + 3];
        bias_s[tid] = s * v;
    }

    float acc[8][8];
    #pragma unroll
    for (int i = 0; i < 8; ++i)
        #pragma unroll
        for (int k = 0; k < 8; ++k) acc[i][k] = 0.f;

    const int jg = tid >> 5;   // 0..7
    const int tg = tid & 31;   // 0..31

    for (int kc = 0; kc < 10; ++kc) {
        const int c0 = kc * 8;
        __syncthreads();
        #pragma unroll
        for (int i = 0; i < 2; ++i) {
            int f   = tid + i * 256;
            int cr  = f >> 6;
            int col = f & 63;
            float mu = mlv_b[(size_t)(j0 + col) * 160 + (c0 + cr)];
            float lv = mlv_b[(size_t)(j0 + col) * 160 + (80 + c0 + cr)];
            float iv = __expf(-lv);
            Gt[cr][col]     = s * iv;
            Gt[cr + 8][col] = -2.f * s * mu * iv;
        }
        #pragma unroll
        for (int i = 0; i < 2; ++i) {
            int f   = tid + i * 256;
            int row = f >> 6;
            int c4  = f & 63;
            int t   = t0 + c4 * 4;
            float4 v = (t + 3 < MELT)
                ? *(const float4*)&ms_b[(size_t)(c0 + row) * MELT + t]
                : make_float4(0.f, 0.f, 0.f, 0.f);
            *(float4*)&Ft[row][c4 * 4] =
                make_float4(v.x * v.x, v.y * v.y, v.z * v.z, v.w * v.w);
            *(float4*)&Ft[row + 8][c4 * 4] = v;
        }
        __syncthreads();
        #pragma unroll
        for (int k = 0; k < 16; ++k) {
            float4 g0 = *(const float4*)&Gt[k][jg * 8];
            float4 g1 = *(const float4*)&Gt[k][jg * 8 + 4];
            float4 f0 = *(const float4*)&Ft[k][tg * 8];
            float4 f1 = *(const float4*)&Ft[k][tg * 8 + 4];
            float ga[8] = {g0.x, g0.y, g0.z, g0.w, g1.x, g1.y, g1.z, g1.w};
            float fa[8] = {f0.x, f0.y, f0.z, f0.w, f1.x, f1.y, f1.z, f1.w};
            #pragma unroll
            for (int ji = 0; ji < 8; ++ji)
                #pragma unroll
                for (int ti = 0; ti < 8; ++ti)
                    acc[ji][ti] = fmaf(ga[ji], fa[ti], acc[ji][ti]);
        }
    }

    #pragma unroll
    for (int ji = 0; ji < 8; ++ji) {
        int j = j0 + jg * 8 + ji;
        float bs = bias_s[jg * 8 + ji];
        float* orow = out_lp + (size_t)(b * TXT + j) * MELT;
        float* srow = has_S ? (lpS + (size_t)b * DIAG * TXT + j) : nullptr;
        #pragma unroll
        for (int ti = 0; ti < 8; ++ti) {
            int t = t0 + tg * 8 + ti;
            if (t < MELT) {
                float v = acc[ji][ti] + bs;
                orow[t] = v;
                if (has_S)
                    srow[(size_t)(t + j) * TXT] = exp2f(fmaf(v, L2E, EPSL2));
            }
        }
    }
}

// ---------------------------------------------------------------------------
// Kernel B: forward DP v6 — LINEAR DOMAIN (scaled forward algorithm).
// alpha held as (mantissa m in [0.5,1), int exponent k). Step:
//   K = max(k,kn); t = (ldexp(m,k-K) + ldexp(mn,kn-K)) * p;  renorm via bits.
// No transcendentals on the serial chain (chain ~28 cy vs ~200 for exp/log).
// Systolic skew i = t + l, 2-deep shuffle pipeline for (m,k), LDS ring
// carries (m,k) pairs, 3-buffer prefetch of prebaked p values.
// ---------------------------------------------------------------------------
__global__ __launch_bounds__(320, 1) void dp_kernel(
    const float* __restrict__ lpS,   // (B,DIAG,320) p = 2^(lp*L2E+EPSL2)
    const int* __restrict__ tlen,
    const int* __restrict__ mlen,
    float* __restrict__ res,
    float* __restrict__ out0)
{
    __shared__ float bnd_m[4][2056];
    __shared__ int   bnd_k[4][2056];
    __shared__ int   prog[4];

    const int b    = blockIdx.x;
    const int tid  = threadIdx.x;
    const int w    = tid >> 6;
    const int l    = tid & 63;
    const int j    = tid;
    const int tend = mlen[b] - 1;
    const int tl   = tlen[b];

    if (tid < 4) prog[tid] = 0;

    const float* rowp = lpS + (size_t)b * DIAG * TXT + j;   // + i*TXT

    float m; int k;
    {
        float p00 = rowp[0];
        if (j == 0) {
            unsigned u = __float_as_uint(p00);
            m = __uint_as_float((u & 0x807FFFFFu) | 0x3F000000u);
            k = (int)((u >> 23) & 0xFFu) - 126;
        } else { m = 0.f; k = KZERO; }
    }
    float mF = m; int kF = k;

    if (l == 63 && w < 4) { bnd_m[w][0] = 0.f; bnd_k[w][0] = KZERO; }
    __syncthreads();

    if (w * 64 > tl - 1) return;   // wave entirely above needed j range

    float pm = __shfl_up(m, 1);
    int   pk = __shfl_up(k, 1);
    float ptAm = (l == 1) ? 0.f   : pm;
    int   ptAk = (l == 1) ? KZERO : pk;
    float ptBm = pm;
    int   ptBk = pk;

    const bool is0     = (l == 0);
    const bool isPub   = (l == 63) && (w < 4);
    const bool hasRing = (w > 0);
    int seen = 0;

    const int imax = tend + 63;

    float PA[8], PB[8], PC[8];
    #pragma unroll
    for (int q = 0; q < 8; ++q) PA[q] = rowp[(size_t)(1 + q) * TXT];
    #pragma unroll
    for (int q = 0; q < 8; ++q) PB[q] = rowp[(size_t)(9 + q) * TXT];
    const float* pref = rowp + (size_t)17 * TXT;

#define RING_RD(BM_, BK_, T0_)                                               \
    {                                                                        \
        float4 r0_ = *(const float4*)&bnd_m[w - 1][T0_];                     \
        float4 r1_ = *(const float4*)&bnd_m[w - 1][(T0_) + 4];               \
        int4   s0_ = *(const int4*)&bnd_k[w - 1][T0_];                       \
        int4   s1_ = *(const int4*)&bnd_k[w - 1][(T0_) + 4];                 \
        BM_[0]=r0_.x; BM_[1]=r0_.y; BM_[2]=r0_.z; BM_[3]=r0_.w;              \
        BM_[4]=r1_.x; BM_[5]=r1_.y; BM_[6]=r1_.z; BM_[7]=r1_.w;              \
        BK_[0]=s0_.x; BK_[1]=s0_.y; BK_[2]=s0_.z; BK_[3]=s0_.w;              \
        BK_[4]=s1_.x; BK_[5]=s1_.y; BK_[6]=s1_.z; BK_[7]=s1_.w;              \
    }
#define RING_POLL(NEED_)                                                     \
    if (seen < (NEED_)) {                                                    \
        int tgt_ = (NEED_) + 32;                                             \
        if (tgt_ > tend - 1) tgt_ = tend - 1;                                \
        if (tgt_ < (NEED_)) tgt_ = (NEED_);                                  \
        volatile int* pv_ = &prog[w - 1];                                    \
        int v_ = *pv_;                                                       \
        while (v_ < tgt_) { __builtin_amdgcn_s_sleep(1); v_ = *pv_; }        \
        seen = v_;                                                           \
    }

    float bqCm[8]; int bqCk[8];
    if (hasRing) {
        RING_POLL(7)
        RING_RD(bqCm, bqCk, 0)
    } else {
        #pragma unroll
        for (int q = 0; q < 8; ++q) { bqCm[q] = 0.f; bqCk[q] = KZERO; }
    }

// one linear-domain DP step (the serial chain: no transcendentals)
#define STEP_LIN(Pc_, q_, MQ_, KQ_)                                          \
    {                                                                        \
        float mn_ = is0 ? bqCm[q_] : ptAm;                                   \
        int   kn_ = is0 ? bqCk[q_] : ptAk;                                   \
        int   K_  = (k > kn_) ? k : kn_;                                     \
        float a_  = ldexpf(m,   k  - K_);                                    \
        float b_  = ldexpf(mn_, kn_ - K_);                                   \
        float t_  = (a_ + b_) * Pc_[q_];                                     \
        unsigned u_ = __float_as_uint(t_);                                   \
        m = __uint_as_float((u_ & 0x807FFFFFu) | 0x3F000000u);               \
        k = K_ + (int)((u_ >> 23) & 0xFFu) - 126;                            \
        MQ_ = m; KQ_ = k;                                                    \
        float nsm_ = __shfl_up(m, 1);                                        \
        int   nsk_ = __shfl_up(k, 1);                                        \
        ptAm = ptBm; ptBm = nsm_;                                            \
        ptAk = ptBk; ptBk = nsk_;                                            \
    }

#define GROUP_S(Pc_, Pl_, I0_)                                               \
{                                                                            \
    float bqNm[8]; int bqNk[8];                                              \
    if (hasRing) {                                                           \
        const int nt0_ = (I0_) + 7;                                          \
        RING_POLL(nt0_ + 7)                                                  \
        RING_RD(bqNm, bqNk, nt0_)                                            \
    } else {                                                                 \
        _Pragma("unroll") for (int q_=0;q_<8;++q_)                           \
            { bqNm[q_] = 0.f; bqNk[q_] = KZERO; }                            \
    }                                                                        \
    _Pragma("unroll") for (int q_=0;q_<8;++q_)                               \
        Pl_[q_] = pref[(size_t)q_ * TXT];                                    \
    float mq[8]; int kq[8];                                                  \
    _Pragma("unroll")                                                        \
    for (int q_=0;q_<8;++q_) STEP_LIN(Pc_, q_, mq[q_], kq[q_])               \
    if (isPub) {                                                             \
        const int t63_ = (I0_) - 63;                                         \
        if (t63_ >= 1) {                                                     \
            _Pragma("unroll") for (int q_=0;q_<8;++q_) {                     \
                bnd_m[w][t63_ + q_] = mq[q_];                                \
                bnd_k[w][t63_ + q_] = kq[q_];                                \
            }                                                                \
        } else {                                                             \
            _Pragma("unroll") for (int q_=0;q_<8;++q_)                       \
                if (t63_ + q_ >= 1) {                                        \
                    bnd_m[w][t63_ + q_] = mq[q_];                            \
                    bnd_k[w][t63_ + q_] = kq[q_];                            \
                }                                                            \
        }                                                                    \
        __asm__ volatile("s_waitcnt lgkmcnt(0)" ::: "memory");               \
        int pgv_ = t63_ + 7;                                                 \
        if (pgv_ >= 1) prog[w] = pgv_;                                       \
    }                                                                        \
    pref += (size_t)8 * TXT;                                                 \
    _Pragma("unroll") for (int q_=0;q_<8;++q_)                               \
        { bqCm[q_] = bqNm[q_]; bqCk[q_] = bqNk[q_]; }                        \
}

#define GROUP_T(Pc_, Pl_, I0_)                                               \
{                                                                            \
    float bqNm[8]; int bqNk[8];                                              \
    if (hasRing) {                                                           \
        const int nt0_ = (I0_) + 7;                                          \
        int need_ = nt0_ + 7; if (need_ > tend - 1) need_ = tend - 1;        \
        RING_POLL(need_)                                                     \
        const int rb_ = nt0_ > 2048 ? 2048 : nt0_;                           \
        RING_RD(bqNm, bqNk, rb_)                                             \
    } else {                                                                 \
        _Pragma("unroll") for (int q_=0;q_<8;++q_)                           \
            { bqNm[q_] = 0.f; bqNk[q_] = KZERO; }                            \
    }                                                                        \
    _Pragma("unroll") for (int q_=0;q_<8;++q_)                               \
        Pl_[q_] = pref[(size_t)q_ * TXT];                                    \
    float mq[8]; int kq[8];                                                  \
    const int vt_ = (I0_) - l;                                               \
    _Pragma("unroll")                                                        \
    for (int q_=0;q_<8;++q_) {                                               \
        STEP_LIN(Pc_, q_, mq[q_], kq[q_])                                    \
        bool c_ = (vt_ + q_ == tend);                                        \
        mF = c_ ? m : mF;                                                    \
        kF = c_ ? k : kF;                                                    \
    }                                                                        \
    if (isPub) {                                                             \
        const int t63_ = (I0_) - 63;                                         \
        _Pragma("unroll") for (int q_=0;q_<8;++q_) {                         \
            int tq_ = t63_ + q_;                                             \
            if (tq_ >= 1 && tq_ <= tend) {                                   \
                bnd_m[w][tq_] = mq[q_];                                      \
                bnd_k[w][tq_] = kq[q_];                                      \
            }                                                                \
        }                                                                    \
        __asm__ volatile("s_waitcnt lgkmcnt(0)" ::: "memory");               \
        int pgv_ = t63_ + 7; if (pgv_ > tend) pgv_ = tend;                   \
        if (pgv_ >= 1) prog[w] = pgv_;                                       \
    }                                                                        \
    pref += (size_t)8 * TXT;                                                 \
    _Pragma("unroll") for (int q_=0;q_<8;++q_)                               \
        { bqCm[q_] = bqNm[q_]; bqCk[q_] = bqNk[q_]; }                        \
}

    int i0 = 1;
    const int sEnd = tend - 23;   // steady: latch can't fire
    int ph = 0;
    while (i0 <= sEnd) {
        GROUP_S(PA, PC, i0); i0 += 8;
        if (i0 > sEnd) { ph = 1; break; }
        GROUP_S(PB, PA, i0); i0 += 8;
        if (i0 > sEnd) { ph = 2; break; }
        GROUP_S(PC, PB, i0); i0 += 8;
    }
    if (ph == 1) {
        #pragma unroll
        for (int q = 0; q < 8; ++q) {
            float tmp = PA[q]; PA[q] = PB[q]; PB[q] = PC[q]; PC[q] = tmp;
        }
    } else if (ph == 2) {
        #pragma unroll
        for (int q = 0; q < 8; ++q) {
            float tmp = PA[q]; PA[q] = PC[q]; PC[q] = PB[q]; PB[q] = tmp;
        }
    }
    while (i0 <= imax) {
        GROUP_T(PA, PC, i0); i0 += 8;
        if (i0 > imax) break;
        GROUP_T(PB, PA, i0); i0 += 8;
        if (i0 > imax) break;
        GROUP_T(PC, PB, i0); i0 += 8;
    }

#undef GROUP_S
#undef GROUP_T
#undef STEP_LIN
#undef RING_RD
#undef RING_POLL

    if (j == tl - 1) {
        float v = ((float)kF + log2f(mF)) * LN2 / (float)(tend + 1);
        if (res) res[b] = v;
        else     atomicAdd(out0, -v / (float)BATCH);
    }
}

// ---------------------------------------------------------------------------
// Fallback DP (log-domain, reads raw out_lp rows) for small ws. (r6 version)
// ---------------------------------------------------------------------------
__global__ __launch_bounds__(320, 1) void dp_kernel_fb(
    const float* __restrict__ lp,
    const int* __restrict__ tlen,
    const int* __restrict__ mlen,
    float* __restrict__ res,
    float* __restrict__ out0)
{
    __shared__ float bnd[4][2056];
    __shared__ int   prog[4];

    const int b    = blockIdx.x;
    const int tid  = threadIdx.x;
    const int w    = tid >> 6;
    const int l    = tid & 63;
    const int j    = tid;
    const int tend = mlen[b] - 1;
    const int tl   = tlen[b];

    if (tid < 4) prog[tid] = 0;

    const float* lprow = lp + (size_t)(b * TXT + j) * MELT;
    float first = lp[(size_t)b * TXT * MELT];
    float A    = (j == 0) ? first * L2E : -PADM;
    float Afin = A;

    if (l == 63 && w < 4) bnd[w][0] = -PADM;
    __syncthreads();

    float prime = __shfl_up(A, 1);
    float ptA = (l == 1) ? -PADM : prime;
    float ptB = prime;

    const bool is0     = (l == 0);
    const bool isPub   = (l == 63) && (w < 4);
    const bool hasRing = (w > 0);
    int seen = 0;

    const int imax = tend + 63;

    float PA[8], PB[8], PC[8];
    #pragma unroll
    for (int q = 0; q < 8; ++q) PA[q] = lprow[1 + q - l];
    #pragma unroll
    for (int q = 0; q < 8; ++q) PB[q] = lprow[9 + q - l];
    #pragma unroll
    for (int q = 0; q < 8; ++q) PA[q] = fmaf(PA[q], L2E, EPSL2);

    const float* pref = lprow + 17 - l;

#define FRING_S(I0_)                                                         \
    float bq[8];                                                             \
    if (hasRing) {                                                           \
        const int t0_ = (I0_) - 1;                                           \
        const int need_ = t0_ + 7;                                           \
        if (seen < need_) {                                                  \
            volatile int* pv_ = &prog[w - 1];                                \
            int v_ = *pv_;                                                   \
            while (v_ < need_) { __builtin_amdgcn_s_sleep(1); v_ = *pv_; }   \
            seen = v_;                                                       \
        }                                                                    \
        float4 r0_ = *(const float4*)&bnd[w - 1][t0_];                       \
        float4 r1_ = *(const float4*)&bnd[w - 1][t0_ + 4];                   \
        bq[0]=r0_.x; bq[1]=r0_.y; bq[2]=r0_.z; bq[3]=r0_.w;                  \
        bq[4]=r1_.x; bq[5]=r1_.y; bq[6]=r1_.z; bq[7]=r1_.w;                  \
    } else {                                                                 \
        _Pragma("unroll") for (int q_=0;q_<8;++q_) bq[q_] = -PADM;           \
    }

#define FGROUP_S(Pc_, Pm_, Pl_, I0_)                                         \
{                                                                            \
    FRING_S(I0_)                                                             \
    _Pragma("unroll") for (int q_=0;q_<8;++q_) Pl_[q_] = pref[q_];           \
    float aq[8];                                                             \
    _Pragma("unroll")                                                        \
    for (int q_=0;q_<8;++q_) {                                               \
        float pt_ = is0 ? bq[q_] : ptA;                                      \
        float m_  = fmaxf(A, pt_);                                           \
        float d_  = A - pt_;                                                 \
        float e_  = __builtin_amdgcn_exp2f(-fabsf(d_));                      \
        float lg_ = __builtin_amdgcn_logf(1.0f + e_);                        \
        A = m_ + lg_ + Pc_[q_];                                              \
        aq[q_] = A;                                                          \
        float ns_ = __shfl_up(A, 1);                                         \
        ptA = ptB; ptB = ns_;                                                \
    }                                                                        \
    if (isPub) {                                                             \
        const int t63_ = (I0_) - 63;                                         \
        if (t63_ >= 1) {                                                     \
            _Pragma("unroll") for (int q_=0;q_<8;++q_)                       \
                bnd[w][t63_ + q_] = aq[q_];                                  \
        } else {                                                             \
            _Pragma("unroll") for (int q_=0;q_<8;++q_)                       \
                if (t63_ + q_ >= 1) bnd[w][t63_ + q_] = aq[q_];              \
        }                                                                    \
        __asm__ volatile("s_waitcnt lgkmcnt(0)" ::: "memory");               \
        int pgv_ = t63_ + 7;                                                 \
        if (pgv_ >= 1) prog[w] = pgv_;                                       \
    }                                                                        \
    pref += 8;                                                               \
    _Pragma("unroll") for (int q_=0;q_<8;++q_)                               \
        Pm_[q_] = fmaf(Pm_[q_], L2E, EPSL2);                                 \
}

#define FGROUP_T(Pc_, Pm_, Pl_, I0_)                                         \
{                                                                            \
    float bq[8];                                                             \
    if (hasRing) {                                                           \
        const int t0_ = (I0_) - 1;                                           \
        int need_ = t0_ + 7; if (need_ > tend - 1) need_ = tend - 1;         \
        if (need_ >= 1 && seen < need_) {                                    \
            volatile int* pv_ = &prog[w - 1];                                \
            int v_ = *pv_;                                                   \
            while (v_ < need_) { __builtin_amdgcn_s_sleep(1); v_ = *pv_; }   \
            seen = v_;                                                       \
        }                                                                    \
        const int rb_ = t0_ > 2048 ? 2048 : t0_;                             \
        float4 r0_ = *(const float4*)&bnd[w - 1][rb_];                       \
        float4 r1_ = *(const float4*)&bnd[w - 1][rb_ + 4];                   \
        bq[0]=r0_.x; bq[1]=r0_.y; bq[2]=r0_.z; bq[3]=r0_.w;                  \
        bq[4]=r1_.x; bq[5]=r1_.y; bq[6]=r1_.z; bq[7]=r1_.w;                  \
    } else {                                                                 \
        _Pragma("unroll") for (int q_=0;q_<8;++q_) bq[q_] = -PADM;           \
    }                                                                        \
    _Pragma("unroll") for (int q_=0;q_<8;++q_) {                             \
        int t_ = (I0_) + 16 + q_ - l;                                        \
        t_ = t_ < 0 ? 0 : (t_ > tend ? tend : t_);                           \
        Pl_[q_] = lprow[t_];                                                 \
    }                                                                        \
    float aq[8];                                                             \
    const int vt_ = (I0_) - l;                                               \
    _Pragma("unroll")                                                        \
    for (int q_=0;q_<8;++q_) {                                               \
        float pt_ = is0 ? bq[q_] : ptA;                                      \
        float m_  = fmaxf(A, pt_);                                           \
        float d_  = A - pt_;                                                 \
        float e_  = __builtin_amdgcn_exp2f(-fabsf(d_));                      \
        float lg_ = __builtin_amdgcn_logf(1.0f + e_);                        \
        A = m_ + lg_ + Pc_[q_];                                              \
        aq[q_] = A;                                                          \
        Afin = (vt_ + q_ == tend) ? A : Afin;                                \
        float ns_ = __shfl_up(A, 1);                                         \
        ptA = ptB; ptB = ns_;                                                \
    }                                                                        \
    if (isPub) {                                                             \
        const int t63_ = (I0_) - 63;                                         \
        _Pragma("unroll") for (int q_=0;q_<8;++q_) {                         \
            int tq_ = t63_ + q_;                                             \
            if (tq_ >= 1 && tq_ <= tend) bnd[w][tq_] = aq[q_];               \
        }                                                                    \
        __asm__ volatile("s_waitcnt lgkmcnt(0)" ::: "memory");               \
        int pgv_ = t63_ + 7; if (pgv_ > tend) pgv_ = tend;                   \
        if (pgv_ >= 1) prog[w] = pgv_;                                       \
    }                                                                        \
    _Pragma("unroll") for (int q_=0;q_<8;++q_)                               \
        Pm_[q_] = fmaf(Pm_[q_], L2E, EPSL2);                                 \
}

    int i0 = 1;
    const int sEnd = tend - 23;
    int ph = 0;
    while (i0 <= sEnd) {
        FGROUP_S(PA, PB, PC, i0); i0 += 8;
        if (i0 > sEnd) { ph = 1; break; }
        FGROUP_S(PB, PC, PA, i0); i0 += 8;
        if (i0 > sEnd) { ph = 2; break; }
        FGROUP_S(PC, PA, PB, i0); i0 += 8;
    }
    if (ph == 1) {
        #pragma unroll
        for (int q = 0; q < 8; ++q) {
            float tmp = PA[q]; PA[q] = PB[q]; PB[q] = PC[q]; PC[q] = tmp;
        }
    } else if (ph == 2) {
        #pragma unroll
        for (int q = 0; q < 8; ++q) {
            float tmp = PA[q]; PA[q] = PC[q]; PC[q] = PB[q]; PB[q] = tmp;
        }
    }
    while (i0 <= imax) {
        FGROUP_T(PA, PB, PC, i0); i0 += 8;
        if (i0 > imax) break;
        FGROUP_T(PB, PC, PA, i0); i0 += 8;
        if (i0 > imax) break;
        FGROUP_T(PC, PA, PB, i0); i0 += 8;
    }

#undef FGROUP_S
#undef FGROUP_T
#undef FRING_S

    if (j == tl - 1) {
        float v = Afin * LN2 / (float)(tend + 1);
        if (res) res[b] = v;
        else     atomicAdd(out0, -v / (float)BATCH);
    }
}

__global__ void zero1_kernel(float* out0) { out0[0] = 0.f; }

__global__ void fin_kernel(const float* __restrict__ res, float* __restrict__ out0)
{
    int l = threadIdx.x;
    float v = (l < BATCH) ? res[l] : 0.f;
    #pragma unroll
    for (int off = 32; off; off >>= 1) v += __shfl_down(v, off);
    if (l == 0) out0[0] = -(v / (float)BATCH);
}

// ---------------------------------------------------------------------------
extern "C" void kernel_launch(void* const* d_in, const int* in_sizes, int n_in,
                              void* d_out, int out_size, void* d_ws, size_t ws_size,
                              hipStream_t stream)
{
    const float* mlv = (const float*)d_in[0];
    const float* ms  = (const float*)d_in[1];
    const int*   tl  = (const int*)d_in[2];
    const int*   ml  = (const int*)d_in[3];
    float* out    = (float*)d_out;
    float* out_lp = out + 1;

    const size_t lpS_bytes = (size_t)BATCH * DIAG * TXT * sizeof(float);
    bool res_ok = ws_size >= 64;
    bool has_S  = ws_size >= 64 + lpS_bytes;
    float* res = res_ok ? (float*)d_ws : nullptr;
    float* lpS = has_S ? (float*)((char*)d_ws + 64) : nullptr;

    dim3 gA(8, 5, 16);   // t-tiles(256), j-tiles(64), batch
    lp_kernel<<<gA, 256, 0, stream>>>(mlv, ms, out_lp, lpS, has_S ? 1 : 0);

    if (!res_ok) zero1_kernel<<<1, 1, 0, stream>>>(out);
    if (has_S) dp_kernel<<<BATCH, 320, 0, stream>>>(lpS, tl, ml, res, out);
    else       dp_kernel_fb<<<BATCH, 320, 0, stream>>>(out_lp, tl, ml, res, out);
    if (res_ok) fin_kernel<<<1, 64, 0, stream>>>(res, out);
}

// Round 8
// 315.664 us; speedup vs baseline: 1.0108x; 1.0108x over previous
//
#include <hip/hip_runtime.h>

#define BATCH 16
#define TXT   320
#define NMELC 80
#define MELT  2000
#define DIAGS 2224   // rows of skewed lpS: >= tend + 63 + 128 + 24 + slack
#define PADM  1.0e12f
#define EPSC  1e-7f
#define L2E   1.4426950408889634f
#define LN2   0.6931471805599453f
#define EPSL2 1.4426950e-7f

// ---------------------------------------------------------------------------
// Kernel A: log_prob[b,j,t] = s*(xx - 2xm + mm),  s = -0.5/80
// tile 64j x 256t, 256 threads, 8j x 8t per thread (r5 structure).
// lpS[b][t + (j>>1)][j] = lp*L2E + EPS*L2E  (pair-skewed diagonal layout:
// DP lane l reads cols 2l,2l+1 of one row -> coalesced float2).
// ---------------------------------------------------------------------------
__global__ __launch_bounds__(256) void lp_kernel(
    const float* __restrict__ mlv,   // (B,320,160)
    const float* __restrict__ ms,    // (B,80,2000)
    float* __restrict__ out_lp,      // (B,320,2000)  (d_out+1)
    float* __restrict__ lpS,         // (B,DIAGS,320) skewed scratch or null
    int has_S)
{
    __shared__ float Gt[16][64];
    __shared__ float Ft[16][256];
    __shared__ float bias_s[64];
    __shared__ float bias_p[256];

    const int b   = blockIdx.z;
    const int j0  = blockIdx.y * 64;
    const int t0  = blockIdx.x * 256;
    const int tid = threadIdx.x;
    const float s = -0.00625f;  // -0.5/80

    const float* mlv_b = mlv + (size_t)b * TXT * 160;
    const float* ms_b  = ms  + (size_t)b * NMELC * MELT;

    {
        const int jj = tid >> 2;
        const int q  = tid & 3;
        const float* p = mlv_b + (size_t)(j0 + jj) * 160 + q * 20;
        float part = 0.f;
        #pragma unroll
        for (int c = 0; c < 20; ++c) {
            float mu = p[c];
            float lv = p[c + 80];
            float iv = __expf(-lv);
            part += mu * mu * iv + lv;
        }
        bias_p[tid] = part;
    }
    __syncthreads();
    if (tid < 64) {
        float v = bias_p[tid * 4] + bias_p[tid * 4 + 1] +
                  bias_p[tid * 4 + 2] + bias_p[tid * 4 + 3];
        bias_s[tid] = s * v;
    }

    float acc[8][8];
    #pragma unroll
    for (int i = 0; i < 8; ++i)
        #pragma unroll
        for (int k = 0; k < 8; ++k) acc[i][k] = 0.f;

    const int jg = tid >> 5;   // 0..7
    const int tg = tid & 31;   // 0..31

    for (int kc = 0; kc < 10; ++kc) {
        const int c0 = kc * 8;
        __syncthreads();
        #pragma unroll
        for (int i = 0; i < 2; ++i) {
            int f   = tid + i * 256;
            int cr  = f >> 6;
            int col = f & 63;
            float mu = mlv_b[(size_t)(j0 + col) * 160 + (c0 + cr)];
            float lv = mlv_b[(size_t)(j0 + col) * 160 + (80 + c0 + cr)];
            float iv = __expf(-lv);
            Gt[cr][col]     = s * iv;
            Gt[cr + 8][col] = -2.f * s * mu * iv;
        }
        #pragma unroll
        for (int i = 0; i < 2; ++i) {
            int f   = tid + i * 256;
            int row = f >> 6;
            int c4  = f & 63;
            int t   = t0 + c4 * 4;
            float4 v = (t + 3 < MELT)
                ? *(const float4*)&ms_b[(size_t)(c0 + row) * MELT + t]
                : make_float4(0.f, 0.f, 0.f, 0.f);
            *(float4*)&Ft[row][c4 * 4] =
                make_float4(v.x * v.x, v.y * v.y, v.z * v.z, v.w * v.w);
            *(float4*)&Ft[row + 8][c4 * 4] = v;
        }
        __syncthreads();
        #pragma unroll
        for (int k = 0; k < 16; ++k) {
            float4 g0 = *(const float4*)&Gt[k][jg * 8];
            float4 g1 = *(const float4*)&Gt[k][jg * 8 + 4];
            float4 f0 = *(const float4*)&Ft[k][tg * 8];
            float4 f1 = *(const float4*)&Ft[k][tg * 8 + 4];
            float ga[8] = {g0.x, g0.y, g0.z, g0.w, g1.x, g1.y, g1.z, g1.w};
            float fa[8] = {f0.x, f0.y, f0.z, f0.w, f1.x, f1.y, f1.z, f1.w};
            #pragma unroll
            for (int ji = 0; ji < 8; ++ji)
                #pragma unroll
                for (int ti = 0; ti < 8; ++ti)
                    acc[ji][ti] = fmaf(ga[ji], fa[ti], acc[ji][ti]);
        }
    }

    #pragma unroll
    for (int ji = 0; ji < 8; ++ji) {
        int j = j0 + jg * 8 + ji;
        float bs = bias_s[jg * 8 + ji];
        float* orow = out_lp + (size_t)(b * TXT + j) * MELT;
        float* srow = has_S ? (lpS + (size_t)b * DIAGS * TXT + j) : nullptr;
        #pragma unroll
        for (int ti = 0; ti < 8; ++ti) {
            int t = t0 + tg * 8 + ti;
            if (t < MELT) {
                float v = acc[ji][ti] + bs;
                orow[t] = v;
                if (has_S)
                    srow[(size_t)(t + (j >> 1)) * TXT] = fmaf(v, L2E, EPSL2);
            }
        }
    }
}

// ---------------------------------------------------------------------------
// Kernel B: forward DP v7 — 2 j per lane. Lane l owns j=2l,2l+1; skew i=t+l.
// Odd-j update is register-only; even-j needs neighbor's odd value via ONE
// 2-deep-pipelined shfl_up per iteration (per 2 j-steps). 3 waves (192 thr),
// 2 LDS rings (vs 4). Publish uses DS in-order completion (no lgkmcnt(0)).
// ---------------------------------------------------------------------------
__global__ __launch_bounds__(192, 1) void dp_kernel(
    const float* __restrict__ lpS,   // (B,DIAGS,320) pre-scaled log2 domain
    const int* __restrict__ tlen,
    const int* __restrict__ mlen,
    float* __restrict__ res,
    float* __restrict__ out0)
{
    __shared__ float bnd[2][2056];
    __shared__ int   prog[2];

    const int b    = blockIdx.x;
    const int tid  = threadIdx.x;
    const int w    = tid >> 6;
    const int l    = tid & 63;
    const int tend = mlen[b] - 1;
    const int tl   = tlen[b];

    if (tid < 2) prog[tid] = 0;

    // lane reads lpS row (i + 64w), cols (2*tid, 2*tid+1)
    const float* rowp = lpS + (size_t)b * DIAGS * TXT
                      + (size_t)(64 * w) * TXT + 2 * tid;

    float A1 = (tid == 0) ? rowp[0] - EPSL2 : -PADM;   // alpha_0[0]=lp00
    float A2 = -PADM;
    float A1F = A1, A2F = A2;

    if (l == 63 && w < 2) bnd[w][0] = -PADM;
    __syncthreads();

    if (w == 2 && tl < 257) return;   // wave 2 unused (owner lane <= 127)

    float ptA2 = -PADM, ptB2 = -PADM;  // neighbor odd-j alpha, 2-deep pipe
    const bool is0     = (l == 0);
    const bool isPub   = (l == 63) && (w < 2);
    const bool hasRing = (w > 0);
    int seen = 0;

    const int imax = tend + 63;

    float PA[16], PB[16], PC[16];
    #pragma unroll
    for (int q = 0; q < 8; ++q) {
        float2 v = *(const float2*)&rowp[(size_t)(1 + q) * TXT];
        PA[2 * q] = v.x; PA[2 * q + 1] = v.y;
    }
    #pragma unroll
    for (int q = 0; q < 8; ++q) {
        float2 v = *(const float2*)&rowp[(size_t)(9 + q) * TXT];
        PB[2 * q] = v.x; PB[2 * q + 1] = v.y;
    }
    const float* pref = rowp + (size_t)17 * TXT;

#define RING_RD(BQ_, T0_)                                                    \
    {                                                                        \
        float4 r0_ = *(const float4*)&bnd[w - 1][T0_];                       \
        float4 r1_ = *(const float4*)&bnd[w - 1][(T0_) + 4];                 \
        BQ_[0]=r0_.x; BQ_[1]=r0_.y; BQ_[2]=r0_.z; BQ_[3]=r0_.w;              \
        BQ_[4]=r1_.x; BQ_[5]=r1_.y; BQ_[6]=r1_.z; BQ_[7]=r1_.w;              \
    }
#define RING_POLL(NEED_)                                                     \
    if (seen < (NEED_)) {                                                    \
        int tgt_ = (NEED_) + 32;                                             \
        if (tgt_ > tend - 1) tgt_ = tend - 1;                                \
        if (tgt_ < (NEED_)) tgt_ = (NEED_);                                  \
        volatile int* pv_ = &prog[w - 1];                                    \
        int v_ = *pv_;                                                       \
        while (v_ < tgt_) { __builtin_amdgcn_s_sleep(1); v_ = *pv_; }        \
        seen = v_;                                                           \
    }

    float bqC[8];
    if (hasRing) {
        RING_POLL(7)
        RING_RD(bqC, 0)
    } else {
        #pragma unroll
        for (int q = 0; q < 8; ++q) bqC[q] = -PADM;
    }

// one iteration = 2 DP j-steps; only n2 crosses lanes
#define STEP2(Pc_, q_, AQ_)                                                  \
    {                                                                        \
        float pt_ = is0 ? bqC[q_] : ptA2;                                    \
        float m1_ = fmaxf(A1, pt_);                                          \
        float d1_ = A1 - pt_;                                                \
        float e1_ = __builtin_amdgcn_exp2f(-fabsf(d1_));                     \
        float g1_ = __builtin_amdgcn_logf(1.0f + e1_);                       \
        float n1_ = m1_ + g1_ + Pc_[2 * q_];                                 \
        float m2_ = fmaxf(A2, A1);                                           \
        float d2_ = A2 - A1;                                                 \
        float e2_ = __builtin_amdgcn_exp2f(-fabsf(d2_));                     \
        float g2_ = __builtin_amdgcn_logf(1.0f + e2_);                       \
        float n2_ = m2_ + g2_ + Pc_[2 * q_ + 1];                             \
        float ns_ = __shfl_up(n2_, 1);                                       \
        ptA2 = ptB2; ptB2 = ns_;                                             \
        A1 = n1_; A2 = n2_; AQ_ = n2_;                                       \
    }

#define GROUP2_S(Pc_, Pl_, I0_)                                              \
{                                                                            \
    float bqN[8];                                                            \
    if (hasRing) {                                                           \
        const int nt0_ = (I0_) + 7;                                          \
        RING_POLL(nt0_ + 7)                                                  \
        RING_RD(bqN, nt0_)                                                   \
    } else {                                                                 \
        _Pragma("unroll") for (int q_=0;q_<8;++q_) bqN[q_] = -PADM;          \
    }                                                                        \
    _Pragma("unroll") for (int q_=0;q_<8;++q_) {                             \
        float2 v_ = *(const float2*)&pref[(size_t)q_ * TXT];                 \
        Pl_[2*q_] = v_.x; Pl_[2*q_+1] = v_.y;                                \
    }                                                                        \
    float aq2[8];                                                            \
    _Pragma("unroll")                                                        \
    for (int q_=0;q_<8;++q_) STEP2(Pc_, q_, aq2[q_])                         \
    if (isPub) {                                                             \
        const int t63_ = (I0_) - 63;                                         \
        if (t63_ >= 1) {                                                     \
            _Pragma("unroll") for (int q_=0;q_<8;++q_)                       \
                bnd[w][t63_ + q_] = aq2[q_];                                 \
        } else {                                                             \
            _Pragma("unroll") for (int q_=0;q_<8;++q_)                       \
                if (t63_ + q_ >= 1) bnd[w][t63_ + q_] = aq2[q_];             \
        }                                                                    \
        __asm__ volatile("" ::: "memory");  /* DS pipe is in-order */        \
        int pgv_ = t63_ + 7;                                                 \
        if (pgv_ >= 1) prog[w] = pgv_;                                       \
    }                                                                        \
    pref += (size_t)8 * TXT;                                                 \
    _Pragma("unroll") for (int q_=0;q_<8;++q_) bqC[q_] = bqN[q_];            \
}

#define GROUP2_T(Pc_, Pl_, I0_)                                              \
{                                                                            \
    float bqN[8];                                                            \
    if (hasRing) {                                                           \
        const int nt0_ = (I0_) + 7;                                          \
        int need_ = nt0_ + 7; if (need_ > tend - 1) need_ = tend - 1;        \
        RING_POLL(need_)                                                     \
        const int rb_ = nt0_ > 2048 ? 2048 : nt0_;                           \
        RING_RD(bqN, rb_)                                                    \
    } else {                                                                 \
        _Pragma("unroll") for (int q_=0;q_<8;++q_) bqN[q_] = -PADM;          \
    }                                                                        \
    _Pragma("unroll") for (int q_=0;q_<8;++q_) {                             \
        float2 v_ = *(const float2*)&pref[(size_t)q_ * TXT];                 \
        Pl_[2*q_] = v_.x; Pl_[2*q_+1] = v_.y;                                \
    }                                                                        \
    float aq2[8];                                                            \
    const int vt_ = (I0_) - l;                                               \
    _Pragma("unroll")                                                        \
    for (int q_=0;q_<8;++q_) {                                               \
        STEP2(Pc_, q_, aq2[q_])                                              \
        bool c_ = (vt_ + q_ == tend);                                        \
        A1F = c_ ? A1 : A1F;                                                 \
        A2F = c_ ? A2 : A2F;                                                 \
    }                                                                        \
    if (isPub) {                                                             \
        const int t63_ = (I0_) - 63;                                         \
        _Pragma("unroll") for (int q_=0;q_<8;++q_) {                         \
            int tq_ = t63_ + q_;                                             \
            if (tq_ >= 1 && tq_ <= tend) bnd[w][tq_] = aq2[q_];              \
        }                                                                    \
        __asm__ volatile("" ::: "memory");                                   \
        int pgv_ = t63_ + 7; if (pgv_ > tend) pgv_ = tend;                   \
        if (pgv_ >= 1) prog[w] = pgv_;                                       \
    }                                                                        \
    pref += (size_t)8 * TXT;                                                 \
    _Pragma("unroll") for (int q_=0;q_<8;++q_) bqC[q_] = bqN[q_];            \
}

    int i0 = 1;
    const int sEnd = tend - 23;   // steady: latch can't fire, loads in-bounds
    int ph = 0;
    while (i0 <= sEnd) {
        GROUP2_S(PA, PC, i0); i0 += 8;
        if (i0 > sEnd) { ph = 1; break; }
        GROUP2_S(PB, PA, i0); i0 += 8;
        if (i0 > sEnd) { ph = 2; break; }
        GROUP2_S(PC, PB, i0); i0 += 8;
    }
    if (ph == 1) {
        #pragma unroll
        for (int q = 0; q < 16; ++q) {
            float tmp = PA[q]; PA[q] = PB[q]; PB[q] = PC[q]; PC[q] = tmp;
        }
    } else if (ph == 2) {
        #pragma unroll
        for (int q = 0; q < 16; ++q) {
            float tmp = PA[q]; PA[q] = PC[q]; PC[q] = PB[q]; PB[q] = tmp;
        }
    }
    while (i0 <= imax) {
        GROUP2_T(PA, PC, i0); i0 += 8;
        if (i0 > imax) break;
        GROUP2_T(PB, PA, i0); i0 += 8;
        if (i0 > imax) break;
        GROUP2_T(PC, PB, i0); i0 += 8;
    }

#undef GROUP2_S
#undef GROUP2_T
#undef STEP2
#undef RING_RD
#undef RING_POLL

    if (tid == ((tl - 1) >> 1)) {
        float Af = ((tl - 1) & 1) ? A2F : A1F;
        float v = Af * LN2 / (float)(tend + 1);
        if (res) res[b] = v;
        else     atomicAdd(out0, -v / (float)BATCH);
    }
}

// ---------------------------------------------------------------------------
// Fallback DP (r6 log-domain, reads raw out_lp rows) for small ws.
// ---------------------------------------------------------------------------
__global__ __launch_bounds__(320, 1) void dp_kernel_fb(
    const float* __restrict__ lp,
    const int* __restrict__ tlen,
    const int* __restrict__ mlen,
    float* __restrict__ res,
    float* __restrict__ out0)
{
    __shared__ float bnd[4][2056];
    __shared__ int   prog[4];

    const int b    = blockIdx.x;
    const int tid  = threadIdx.x;
    const int w    = tid >> 6;
    const int l    = tid & 63;
    const int j    = tid;
    const int tend = mlen[b] - 1;
    const int tl   = tlen[b];

    if (tid < 4) prog[tid] = 0;

    const float* lprow = lp + (size_t)(b * TXT + j) * MELT;
    float first = lp[(size_t)b * TXT * MELT];
    float A    = (j == 0) ? first * L2E : -PADM;
    float Afin = A;

    if (l == 63 && w < 4) bnd[w][0] = -PADM;
    __syncthreads();

    float prime = __shfl_up(A, 1);
    float ptA = (l == 1) ? -PADM : prime;
    float ptB = prime;

    const bool is0     = (l == 0);
    const bool isPub   = (l == 63) && (w < 4);
    const bool hasRing = (w > 0);
    int seen = 0;

    const int imax = tend + 63;

    float PA[8], PB[8], PC[8];
    #pragma unroll
    for (int q = 0; q < 8; ++q) PA[q] = lprow[1 + q - l];
    #pragma unroll
    for (int q = 0; q < 8; ++q) PB[q] = lprow[9 + q - l];
    #pragma unroll
    for (int q = 0; q < 8; ++q) PA[q] = fmaf(PA[q], L2E, EPSL2);

    const float* pref = lprow + 17 - l;

#define FRING_S(I0_)                                                         \
    float bq[8];                                                             \
    if (hasRing) {                                                           \
        const int t0_ = (I0_) - 1;                                           \
        const int need_ = t0_ + 7;                                           \
        if (seen < need_) {                                                  \
            volatile int* pv_ = &prog[w - 1];                                \
            int v_ = *pv_;                                                   \
            while (v_ < need_) { __builtin_amdgcn_s_sleep(1); v_ = *pv_; }   \
            seen = v_;                                                       \
        }                                                                    \
        float4 r0_ = *(const float4*)&bnd[w - 1][t0_];                       \
        float4 r1_ = *(const float4*)&bnd[w - 1][t0_ + 4];                   \
        bq[0]=r0_.x; bq[1]=r0_.y; bq[2]=r0_.z; bq[3]=r0_.w;                  \
        bq[4]=r1_.x; bq[5]=r1_.y; bq[6]=r1_.z; bq[7]=r1_.w;                  \
    } else {                                                                 \
        _Pragma("unroll") for (int q_=0;q_<8;++q_) bq[q_] = -PADM;           \
    }

#define FGROUP_S(Pc_, Pm_, Pl_, I0_)                                         \
{                                                                            \
    FRING_S(I0_)                                                             \
    _Pragma("unroll") for (int q_=0;q_<8;++q_) Pl_[q_] = pref[q_];           \
    float aq[8];                                                             \
    _Pragma("unroll")                                                        \
    for (int q_=0;q_<8;++q_) {                                               \
        float pt_ = is0 ? bq[q_] : ptA;                                      \
        float m_  = fmaxf(A, pt_);                                           \
        float d_  = A - pt_;                                                 \
        float e_  = __builtin_amdgcn_exp2f(-fabsf(d_));                      \
        float lg_ = __builtin_amdgcn_logf(1.0f + e_);                        \
        A = m_ + lg_ + Pc_[q_];                                              \
        aq[q_] = A;                                                          \
        float ns_ = __shfl_up(A, 1);                                         \
        ptA = ptB; ptB = ns_;                                                \
    }                                                                        \
    if (isPub) {                                                             \
        const int t63_ = (I0_) - 63;                                         \
        if (t63_ >= 1) {                                                     \
            _Pragma("unroll") for (int q_=0;q_<8;++q_)                       \
                bnd[w][t63_ + q_] = aq[q_];                                  \
        } else {                                                             \
            _Pragma("unroll") for (int q_=0;q_<8;++q_)                       \
                if (t63_ + q_ >= 1) bnd[w][t63_ + q_] = aq[q_];              \
        }                                                                    \
        __asm__ volatile("s_waitcnt lgkmcnt(0)" ::: "memory");               \
        int pgv_ = t63_ + 7;                                                 \
        if (pgv_ >= 1) prog[w] = pgv_;                                       \
    }                                                                        \
    pref += 8;                                                               \
    _Pragma("unroll") for (int q_=0;q_<8;++q_)                               \
        Pm_[q_] = fmaf(Pm_[q_], L2E, EPSL2);                                 \
}

#define FGROUP_T(Pc_, Pm_, Pl_, I0_)                                         \
{                                                                            \
    float bq[8];                                                             \
    if (hasRing) {                                                           \
        const int t0_ = (I0_) - 1;                                           \
        int need_ = t0_ + 7; if (need_ > tend - 1) need_ = tend - 1;         \
        if (need_ >= 1 && seen < need_) {                                    \
            volatile int* pv_ = &prog[w - 1];                                \
            int v_ = *pv_;                                                   \
            while (v_ < need_) { __builtin_amdgcn_s_sleep(1); v_ = *pv_; }   \
            seen = v_;                                                       \
        }                                                                    \
        const int rb_ = t0_ > 2048 ? 2048 : t0_;                             \
        float4 r0_ = *(const float4*)&bnd[w - 1][rb_];                       \
        float4 r1_ = *(const float4*)&bnd[w - 1][rb_ + 4];                   \
        bq[0]=r0_.x; bq[1]=r0_.y; bq[2]=r0_.z; bq[3]=r0_.w;                  \
        bq[4]=r1_.x; bq[5]=r1_.y; bq[6]=r1_.z; bq[7]=r1_.w;                  \
    } else {                                                                 \
        _Pragma("unroll") for (int q_=0;q_<8;++q_) bq[q_] = -PADM;           \
    }                                                                        \
    _Pragma("unroll") for (int q_=0;q_<8;++q_) {                             \
        int t_ = (I0_) + 16 + q_ - l;                                        \
        t_ = t_ < 0 ? 0 : (t_ > tend ? tend : t_);                           \
        Pl_[q_] = lprow[t_];                                                 \
    }                                                                        \
    float aq[8];                                                             \
    const int vt_ = (I0_) - l;                                               \
    _Pragma("unroll")                                                        \
    for (int q_=0;q_<8;++q_) {                                               \
        float pt_ = is0 ? bq[q_] : ptA;                                      \
        float m_  = fmaxf(A, pt_);                                           \
        float d_  = A - pt_;                                                 \
        float e_  = __builtin_amdgcn_exp2f(-fabsf(d_));                      \
        float lg_ = __builtin_amdgcn_logf(1.0f + e_);                        \
        A = m_ + lg_ + Pc_[q_];                                              \
        aq[q_] = A;                                                          \
        Afin = (vt_ + q_ == tend) ? A : Afin;                                \
        float ns_ = __shfl_up(A, 1);                                         \
        ptA = ptB; ptB = ns_;                                                \
    }                                                                        \
    if (isPub) {                                                             \
        const int t63_ = (I0_) - 63;                                         \
        _Pragma("unroll") for (int q_=0;q_<8;++q_) {                         \
            int tq_ = t63_ + q_;                                             \
            if (tq_ >= 1 && tq_ <= tend) bnd[w][tq_] = aq[q_];               \
        }                                                                    \
        __asm__ volatile("s_waitcnt lgkmcnt(0)" ::: "memory");               \
        int pgv_ = t63_ + 7; if (pgv_ > tend) pgv_ = tend;                   \
        if (pgv_ >= 1) prog[w] = pgv_;                                       \
    }                                                                        \
    _Pragma("unroll") for (int q_=0;q_<8;++q_)                               \
        Pm_[q_] = fmaf(Pm_[q_], L2E, EPSL2);                                 \
}

    int i0 = 1;
    const int sEnd = tend - 23;
    int ph = 0;
    while (i0 <= sEnd) {
        FGROUP_S(PA, PB, PC, i0); i0 += 8;
        if (i0 > sEnd) { ph = 1; break; }
        FGROUP_S(PB, PC, PA, i0); i0 += 8;
        if (i0 > sEnd) { ph = 2; break; }
        FGROUP_S(PC, PA, PB, i0); i0 += 8;
    }
    if (ph == 1) {
        #pragma unroll
        for (int q = 0; q < 8; ++q) {
            float tmp = PA[q]; PA[q] = PB[q]; PB[q] = PC[q]; PC[q] = tmp;
        }
    } else if (ph == 2) {
        #pragma unroll
        for (int q = 0; q < 8; ++q) {
            float tmp = PA[q]; PA[q] = PC[q]; PC[q] = PB[q]; PB[q] = tmp;
        }
    }
    while (i0 <= imax) {
        FGROUP_T(PA, PB, PC, i0); i0 += 8;
        if (i0 > imax) break;
        FGROUP_T(PB, PC, PA, i0); i0 += 8;
        if (i0 > imax) break;
        FGROUP_T(PC, PA, PB, i0); i0 += 8;
    }

#undef FGROUP_S
#undef FGROUP_T
#undef FRING_S

    if (j == tl - 1) {
        float v = Afin * LN2 / (float)(tend + 1);
        if (res) res[b] = v;
        else     atomicAdd(out0, -v / (float)BATCH);
    }
}

__global__ void zero1_kernel(float* out0) { out0[0] = 0.f; }

__global__ void fin_kernel(const float* __restrict__ res, float* __restrict__ out0)
{
    int l = threadIdx.x;
    float v = (l < BATCH) ? res[l] : 0.f;
    #pragma unroll
    for (int off = 32; off; off >>= 1) v += __shfl_down(v, off);
    if (l == 0) out0[0] = -(v / (float)BATCH);
}

// ---------------------------------------------------------------------------
extern "C" void kernel_launch(void* const* d_in, const int* in_sizes, int n_in,
                              void* d_out, int out_size, void* d_ws, size_t ws_size,
                              hipStream_t stream)
{
    const float* mlv = (const float*)d_in[0];
    const float* ms  = (const float*)d_in[1];
    const int*   tl  = (const int*)d_in[2];
    const int*   ml  = (const int*)d_in[3];
    float* out    = (float*)d_out;
    float* out_lp = out + 1;

    const size_t lpS_bytes = (size_t)BATCH * DIAGS * TXT * sizeof(float);
    bool res_ok = ws_size >= 128;
    bool has_S  = ws_size >= 128 + lpS_bytes;
    float* res = res_ok ? (float*)d_ws : nullptr;
    float* lpS = has_S ? (float*)((char*)d_ws + 128) : nullptr;

    dim3 gA(8, 5, 16);   // t-tiles(256), j-tiles(64), batch
    lp_kernel<<<gA, 256, 0, stream>>>(mlv, ms, out_lp, lpS, has_S ? 1 : 0);

    if (!res_ok) zero1_kernel<<<1, 1, 0, stream>>>(out);
    if (has_S) dp_kernel<<<BATCH, 192, 0, stream>>>(lpS, tl, ml, res, out);
    else       dp_kernel_fb<<<BATCH, 320, 0, stream>>>(out_lp, tl, ml, res, out);
    if (res_ok) fin_kernel<<<1, 64, 0, stream>>>(res, out);
}

// Round 9
// 244.696 us; speedup vs baseline: 1.3040x; 1.2900x over previous
//
#include <hip/hip_runtime.h>

#define BATCH 16
#define TXT   320
#define NMELC 80
#define MELT  2000
#define PADM  1.0e12f
#define EPSC  1e-7f
#define L2E   1.4426950408889634f
#define LN2   0.6931471805599453f
#define EPSL2 1.4426950e-7f

// ---------------------------------------------------------------------------
// Kernel A: log_prob[b,j,t] = s*(xx - 2xm + mm),  s = -0.5/80  (r5 structure)
//   c <  80: G = s*inv_var,          F = x^2
//   c >= 80: G = -2*s*mu*inv_var,    F = x
// tile 64j x 256t, 256 threads, 8j x 8t per thread. No scatter.
// ---------------------------------------------------------------------------
__global__ __launch_bounds__(256) void lp_kernel(
    const float* __restrict__ mlv,   // (B,320,160)
    const float* __restrict__ ms,    // (B,80,2000)
    float* __restrict__ out_lp)      // (B,320,2000)  (d_out+1)
{
    __shared__ float Gt[16][64];
    __shared__ float Ft[16][256];
    __shared__ float bias_s[64];
    __shared__ float bias_p[256];

    const int b   = blockIdx.z;
    const int j0  = blockIdx.y * 64;
    const int t0  = blockIdx.x * 256;
    const int tid = threadIdx.x;
    const float s = -0.00625f;  // -0.5/80

    const float* mlv_b = mlv + (size_t)b * TXT * 160;
    const float* ms_b  = ms  + (size_t)b * NMELC * MELT;

    {
        const int jj = tid >> 2;
        const int q  = tid & 3;
        const float* p = mlv_b + (size_t)(j0 + jj) * 160 + q * 20;
        float part = 0.f;
        #pragma unroll
        for (int c = 0; c < 20; ++c) {
            float mu = p[c];
            float lv = p[c + 80];
            float iv = __expf(-lv);
            part += mu * mu * iv + lv;
        }
        bias_p[tid] = part;
    }
    __syncthreads();
    if (tid < 64) {
        float v = bias_p[tid * 4] + bias_p[tid * 4 + 1] +
                  bias_p[tid * 4 + 2] + bias_p[tid * 4 + 3];
        bias_s[tid] = s * v;
    }

    float acc[8][8];
    #pragma unroll
    for (int i = 0; i < 8; ++i)
        #pragma unroll
        for (int k = 0; k < 8; ++k) acc[i][k] = 0.f;

    const int jg = tid >> 5;   // 0..7
    const int tg = tid & 31;   // 0..31

    for (int kc = 0; kc < 10; ++kc) {
        const int c0 = kc * 8;
        __syncthreads();
        #pragma unroll
        for (int i = 0; i < 2; ++i) {
            int f   = tid + i * 256;
            int cr  = f >> 6;
            int col = f & 63;
            float mu = mlv_b[(size_t)(j0 + col) * 160 + (c0 + cr)];
            float lv = mlv_b[(size_t)(j0 + col) * 160 + (80 + c0 + cr)];
            float iv = __expf(-lv);
            Gt[cr][col]     = s * iv;
            Gt[cr + 8][col] = -2.f * s * mu * iv;
        }
        #pragma unroll
        for (int i = 0; i < 2; ++i) {
            int f   = tid + i * 256;
            int row = f >> 6;
            int c4  = f & 63;
            int t   = t0 + c4 * 4;
            float4 v = (t + 3 < MELT)
                ? *(const float4*)&ms_b[(size_t)(c0 + row) * MELT + t]
                : make_float4(0.f, 0.f, 0.f, 0.f);
            *(float4*)&Ft[row][c4 * 4] =
                make_float4(v.x * v.x, v.y * v.y, v.z * v.z, v.w * v.w);
            *(float4*)&Ft[row + 8][c4 * 4] = v;
        }
        __syncthreads();
        #pragma unroll
        for (int k = 0; k < 16; ++k) {
            float4 g0 = *(const float4*)&Gt[k][jg * 8];
            float4 g1 = *(const float4*)&Gt[k][jg * 8 + 4];
            float4 f0 = *(const float4*)&Ft[k][tg * 8];
            float4 f1 = *(const float4*)&Ft[k][tg * 8 + 4];
            float ga[8] = {g0.x, g0.y, g0.z, g0.w, g1.x, g1.y, g1.z, g1.w};
            float fa[8] = {f0.x, f0.y, f0.z, f0.w, f1.x, f1.y, f1.z, f1.w};
            #pragma unroll
            for (int ji = 0; ji < 8; ++ji)
                #pragma unroll
                for (int ti = 0; ti < 8; ++ti)
                    acc[ji][ti] = fmaf(ga[ji], fa[ti], acc[ji][ti]);
        }
    }

    #pragma unroll
    for (int ji = 0; ji < 8; ++ji) {
        int j = j0 + jg * 8 + ji;
        float bs = bias_s[jg * 8 + ji];
        float* orow = out_lp + (size_t)(b * TXT + j) * MELT;
        #pragma unroll
        for (int ti = 0; ti < 8; ++ti) {
            int t = t0 + tg * 8 + ti;
            if (t < MELT) orow[t] = acc[ji][ti] + bs;
        }
    }
}

// ---------------------------------------------------------------------------
// Kernel B: forward DP v8 — 2 j/lane, systolic skew i = t + l, neighbor
// exchange via DPP wave_shr:1 (pure VALU lane shift, NO ds_bpermute on the
// loop). Reads out_lp rows directly (diverged loads, hidden by 3-deep
// prefetch, r4-verified). LDS only for the inter-wave ring (1 read/8 iters,
// prefetched one group ahead). 3 waves, 2 rings.
// ---------------------------------------------------------------------------
__device__ __forceinline__ float dpp_shr1(float x) {
    return __int_as_float(__builtin_amdgcn_update_dpp(
        0, __float_as_int(x), 0x138 /*wave_shr:1*/, 0xF, 0xF, false));
}

__global__ __launch_bounds__(192, 1) void dp_kernel(
    const float* __restrict__ lp,    // (B,320,2000) = out_lp
    const int* __restrict__ tlen,
    const int* __restrict__ mlen,
    float* __restrict__ res,
    float* __restrict__ out0)
{
    __shared__ float bnd[2][2056];
    __shared__ int   prog[2];

    const int b    = blockIdx.x;
    const int tid  = threadIdx.x;
    const int w    = tid >> 6;
    const int l    = tid & 63;
    const int tend = mlen[b] - 1;
    const int tl   = tlen[b];

    if (tid < 2) prog[tid] = 0;

    int j0c = 2 * tid; if (j0c > 318) j0c = 318;   // clamp unused lanes
    const float* r0 = lp + (size_t)(b * TXT + j0c) * MELT;
    const float* r1 = r0 + MELT;

    float A1 = (tid == 0) ? lp[(size_t)b * TXT * MELT] * L2E : -PADM;
    float A2 = -PADM;
    float A1F = A1, A2F = A2;

    if (l == 63 && w < 2) bnd[w][0] = -PADM;
    __syncthreads();

    if (w == 2 && tl < 257) return;   // wave 2 unused

    float ptA2 = -PADM, ptB2 = -PADM;   // neighbor odd-j alpha, 2-deep pipe
    const bool is0     = (l == 0);
    const bool isPub   = (l == 63) && (w < 2);
    const bool hasRing = (w > 0);
    int seen = 0;

    const int imax = tend + 63;

    // 3-deep rotating prefetch: 2 scalar loads / iteration (t = I + q - l)
    float PA[16], PB[16], PC[16];
    #pragma unroll
    for (int q = 0; q < 8; ++q) { PA[2*q] = r0[1 + q - l]; PA[2*q+1] = r1[1 + q - l]; }
    #pragma unroll
    for (int q = 0; q < 8; ++q) { PB[2*q] = r0[9 + q - l]; PB[2*q+1] = r1[9 + q - l]; }
    #pragma unroll
    for (int q = 0; q < 16; ++q) PA[q] = fmaf(PA[q], L2E, EPSL2);

    const float* p0 = r0 + 17 - l;
    const float* p1 = r1 + 17 - l;

#define RING_RD(BQ_, T0_)                                                    \
    {                                                                        \
        float4 r0_ = *(const float4*)&bnd[w - 1][T0_];                       \
        float4 r1_ = *(const float4*)&bnd[w - 1][(T0_) + 4];                 \
        BQ_[0]=r0_.x; BQ_[1]=r0_.y; BQ_[2]=r0_.z; BQ_[3]=r0_.w;              \
        BQ_[4]=r1_.x; BQ_[5]=r1_.y; BQ_[6]=r1_.z; BQ_[7]=r1_.w;              \
    }
#define RING_POLL(NEED_)                                                     \
    if (seen < (NEED_)) {                                                    \
        int tgt_ = (NEED_) + 32;                                             \
        if (tgt_ > tend - 1) tgt_ = tend - 1;                                \
        if (tgt_ < (NEED_)) tgt_ = (NEED_);                                  \
        volatile int* pv_ = &prog[w - 1];                                    \
        int v_ = *pv_;                                                       \
        while (v_ < tgt_) { __builtin_amdgcn_s_sleep(1); v_ = *pv_; }        \
        seen = v_;                                                           \
        __asm__ volatile("" ::: "memory");                                   \
    }

    float bqC[8];
    if (hasRing) {
        RING_POLL(7)
        RING_RD(bqC, 0)
    } else {
        #pragma unroll
        for (int q = 0; q < 8; ++q) bqC[q] = -PADM;
    }

// one iteration = 2 DP j-steps; neighbor via DPP (VALU), no LDS on chain
#define STEP2(Pc_, q_, AQ_)                                                  \
    {                                                                        \
        float pt_ = is0 ? bqC[q_] : ptA2;                                    \
        float m1_ = fmaxf(A1, pt_);                                          \
        float d1_ = A1 - pt_;                                                \
        float e1_ = __builtin_amdgcn_exp2f(-fabsf(d1_));                     \
        float g1_ = __builtin_amdgcn_logf(1.0f + e1_);                       \
        float n1_ = m1_ + g1_ + Pc_[2 * q_];                                 \
        float m2_ = fmaxf(A2, A1);                                           \
        float d2_ = A2 - A1;                                                 \
        float e2_ = __builtin_amdgcn_exp2f(-fabsf(d2_));                     \
        float g2_ = __builtin_amdgcn_logf(1.0f + e2_);                       \
        float n2_ = m2_ + g2_ + Pc_[2 * q_ + 1];                             \
        float ns_ = dpp_shr1(n2_);                                           \
        ptA2 = ptB2; ptB2 = ns_;                                             \
        A1 = n1_; A2 = n2_; AQ_ = n2_;                                       \
    }

#define GROUP2_S(Pc_, Pm_, Pl_, I0_)                                         \
{                                                                            \
    float bqN[8];                                                            \
    if (hasRing) {                                                           \
        const int nt0_ = (I0_) + 7;                                          \
        RING_POLL(nt0_ + 7)                                                  \
        RING_RD(bqN, nt0_)                                                   \
    } else {                                                                 \
        _Pragma("unroll") for (int q_=0;q_<8;++q_) bqN[q_] = -PADM;          \
    }                                                                        \
    _Pragma("unroll") for (int q_=0;q_<8;++q_) {                             \
        Pl_[2*q_] = p0[q_]; Pl_[2*q_+1] = p1[q_];                            \
    }                                                                        \
    float aq2[8];                                                            \
    _Pragma("unroll")                                                        \
    for (int q_=0;q_<8;++q_) STEP2(Pc_, q_, aq2[q_])                         \
    if (isPub) {                                                             \
        const int t63_ = (I0_) - 63;                                         \
        if (t63_ >= 1) {                                                     \
            _Pragma("unroll") for (int q_=0;q_<8;++q_)                       \
                bnd[w][t63_ + q_] = aq2[q_];                                 \
        } else {                                                             \
            _Pragma("unroll") for (int q_=0;q_<8;++q_)                       \
                if (t63_ + q_ >= 1) bnd[w][t63_ + q_] = aq2[q_];             \
        }                                                                    \
        __asm__ volatile("" ::: "memory");  /* DS pipe is in-order */        \
        int pgv_ = t63_ + 7;                                                 \
        if (pgv_ >= 1) prog[w] = pgv_;                                       \
    }                                                                        \
    p0 += 8; p1 += 8;                                                        \
    _Pragma("unroll") for (int q_=0;q_<16;++q_)                              \
        Pm_[q_] = fmaf(Pm_[q_], L2E, EPSL2);                                 \
    _Pragma("unroll") for (int q_=0;q_<8;++q_) bqC[q_] = bqN[q_];            \
}

#define GROUP2_T(Pc_, Pm_, Pl_, I0_)                                         \
{                                                                            \
    float bqN[8];                                                            \
    if (hasRing) {                                                           \
        const int nt0_ = (I0_) + 7;                                          \
        int need_ = nt0_ + 7; if (need_ > tend - 1) need_ = tend - 1;        \
        RING_POLL(need_)                                                     \
        const int rb_ = nt0_ > 2048 ? 2048 : nt0_;                           \
        RING_RD(bqN, rb_)                                                    \
    } else {                                                                 \
        _Pragma("unroll") for (int q_=0;q_<8;++q_) bqN[q_] = -PADM;          \
    }                                                                        \
    _Pragma("unroll") for (int q_=0;q_<8;++q_) {                             \
        int t_ = (I0_) + 16 + q_ - l;                                        \
        t_ = t_ < 0 ? 0 : (t_ > tend ? tend : t_);                           \
        Pl_[2*q_] = r0[t_]; Pl_[2*q_+1] = r1[t_];                            \
    }                                                                        \
    float aq2[8];                                                            \
    const int vt_ = (I0_) - l;                                               \
    _Pragma("unroll")                                                        \
    for (int q_=0;q_<8;++q_) {                                               \
        STEP2(Pc_, q_, aq2[q_])                                              \
        bool c_ = (vt_ + q_ == tend);                                        \
        A1F = c_ ? A1 : A1F;                                                 \
        A2F = c_ ? A2 : A2F;                                                 \
    }                                                                        \
    if (isPub) {                                                             \
        const int t63_ = (I0_) - 63;                                         \
        _Pragma("unroll") for (int q_=0;q_<8;++q_) {                         \
            int tq_ = t63_ + q_;                                             \
            if (tq_ >= 1 && tq_ <= tend) bnd[w][tq_] = aq2[q_];              \
        }                                                                    \
        __asm__ volatile("" ::: "memory");                                   \
        int pgv_ = t63_ + 7; if (pgv_ > tend) pgv_ = tend;                   \
        if (pgv_ >= 1) prog[w] = pgv_;                                       \
    }                                                                        \
    _Pragma("unroll") for (int q_=0;q_<16;++q_)                              \
        Pm_[q_] = fmaf(Pm_[q_], L2E, EPSL2);                                 \
    _Pragma("unroll") for (int q_=0;q_<8;++q_) bqC[q_] = bqN[q_];            \
}

    int i0 = 1;
    const int sEnd = tend - 23;   // steady: loads in-bounds, latch can't fire
    int ph = 0;
    while (i0 <= sEnd) {
        GROUP2_S(PA, PB, PC, i0); i0 += 8;
        if (i0 > sEnd) { ph = 1; break; }
        GROUP2_S(PB, PC, PA, i0); i0 += 8;
        if (i0 > sEnd) { ph = 2; break; }
        GROUP2_S(PC, PA, PB, i0); i0 += 8;
    }
    if (ph == 1) {
        #pragma unroll
        for (int q = 0; q < 16; ++q) {
            float tmp = PA[q]; PA[q] = PB[q]; PB[q] = PC[q]; PC[q] = tmp;
        }
    } else if (ph == 2) {
        #pragma unroll
        for (int q = 0; q < 16; ++q) {
            float tmp = PA[q]; PA[q] = PC[q]; PC[q] = PB[q]; PB[q] = tmp;
        }
    }
    while (i0 <= imax) {
        GROUP2_T(PA, PB, PC, i0); i0 += 8;
        if (i0 > imax) break;
        GROUP2_T(PB, PC, PA, i0); i0 += 8;
        if (i0 > imax) break;
        GROUP2_T(PC, PA, PB, i0); i0 += 8;
    }

#undef GROUP2_S
#undef GROUP2_T
#undef STEP2
#undef RING_RD
#undef RING_POLL

    if (tid == ((tl - 1) >> 1)) {
        float Af = ((tl - 1) & 1) ? A2F : A1F;
        float v = Af * LN2 / (float)(tend + 1);
        if (res) res[b] = v;
        else     atomicAdd(out0, -v / (float)BATCH);
    }
}

__global__ void zero1_kernel(float* out0) { out0[0] = 0.f; }

__global__ void fin_kernel(const float* __restrict__ res, float* __restrict__ out0)
{
    int l = threadIdx.x;
    float v = (l < BATCH) ? res[l] : 0.f;
    #pragma unroll
    for (int off = 32; off; off >>= 1) v += __shfl_down(v, off);
    if (l == 0) out0[0] = -(v / (float)BATCH);
}

// ---------------------------------------------------------------------------
extern "C" void kernel_launch(void* const* d_in, const int* in_sizes, int n_in,
                              void* d_out, int out_size, void* d_ws, size_t ws_size,
                              hipStream_t stream)
{
    const float* mlv = (const float*)d_in[0];
    const float* ms  = (const float*)d_in[1];
    const int*   tl  = (const int*)d_in[2];
    const int*   ml  = (const int*)d_in[3];
    float* out    = (float*)d_out;
    float* out_lp = out + 1;

    bool res_ok = ws_size >= 64;
    float* res = res_ok ? (float*)d_ws : nullptr;

    dim3 gA(8, 5, 16);   // t-tiles(256), j-tiles(64), batch
    lp_kernel<<<gA, 256, 0, stream>>>(mlv, ms, out_lp);

    if (!res_ok) zero1_kernel<<<1, 1, 0, stream>>>(out);
    dp_kernel<<<BATCH, 192, 0, stream>>>(out_lp, tl, ml, res, out);
    if (res_ok) fin_kernel<<<1, 64, 0, stream>>>(res, out);
}